// Round 1
// baseline (361.119 us; speedup 1.0000x reference)
//
#include <hip/hip_runtime.h>
#include <hip/hip_bf16.h>

#define BB 16384   // batch
#define CC 4000    // agents (real)
#define CP 4096    // agents padded
#define DD 128     // feature dim

typedef __attribute__((ext_vector_type(8))) short short8;
typedef __attribute__((ext_vector_type(4))) float f32x4;

static __device__ __forceinline__ unsigned short f2bf(float f) {
  union { float f; unsigned int u; } v; v.f = f;
  unsigned int u = v.u;
  u += 0x7fffu + ((u >> 16) & 1u);   // RNE
  return (unsigned short)(u >> 16);
}

// ---- kernel 1: agents -> bf16 (padded to CP rows, zeros) + ||a||^2 ----
__global__ void prep_agents_k(const float* __restrict__ agents,
                              unsigned short* __restrict__ Ab,
                              float* __restrict__ an) {
  int c = blockIdx.x;      // 0..CP-1
  int t = threadIdx.x;     // 0..63, each handles 2 elems
  float n = 0.f;
  unsigned int pack = 0u;
  if (c < CC) {
    float2 f = *(const float2*)&agents[c * DD + t * 2];
    n = f.x * f.x + f.y * f.y;
    pack = ((unsigned int)f2bf(f.y) << 16) | (unsigned int)f2bf(f.x);
  }
  ((unsigned int*)Ab)[c * (DD / 2) + t] = pack;
  #pragma unroll
  for (int m = 1; m < 64; m <<= 1) n += __shfl_xor(n, m);
  if (t == 0) an[c] = n;
}

// ---- kernel 2: features -> bf16 + ||f||^2 ; loss_pos (exact f32) for y==0 ----
__global__ void prep_features_k(const float* __restrict__ fsrc,
                                const float* __restrict__ ftgt,
                                const float* __restrict__ agents,
                                const int* __restrict__ labels,
                                unsigned short* __restrict__ Fsb,
                                unsigned short* __restrict__ Ftb,
                                float* __restrict__ fns,
                                float* __restrict__ fnt,
                                float* __restrict__ lp) {
  int b = blockIdx.x;
  int y = blockIdx.y;
  int t = threadIdx.x;  // 0..63
  const float* F = y ? ftgt : fsrc;
  unsigned short* Fb = y ? Ftb : Fsb;
  float2 f = *(const float2*)&F[b * DD + t * 2];
  float n = f.x * f.x + f.y * f.y;
  ((unsigned int*)Fb)[b * (DD / 2) + t] =
      ((unsigned int)f2bf(f.y) << 16) | (unsigned int)f2bf(f.x);
  float pl = 0.f;
  if (y == 0) {
    int lab = labels[b];
    float2 a = *(const float2*)&agents[lab * DD + t * 2];
    float dx = f.x - a.x, dy = f.y - a.y;
    pl = dx * dx + dy * dy;
  }
  #pragma unroll
  for (int m = 1; m < 64; m <<= 1) { n += __shfl_xor(n, m); pl += __shfl_xor(pl, m); }
  if (t == 0) {
    if (y) fnt[b] = n; else fns[b] = n;
    if (y == 0) lp[b] = pl;
  }
}

// ---- kernel 3: masked hinge over dist = fn + an - 2 f.a  (MFMA bf16) ----
// grid (BB/64, 2 {src,tgt}, 2 col-halves); block 256 = 4 waves in 2x2.
__global__ void neg_kernel(const unsigned short* __restrict__ Fsb,
                           const unsigned short* __restrict__ Ftb,
                           const unsigned short* __restrict__ Ab,
                           const float* __restrict__ an,
                           const float* __restrict__ fns,
                           const float* __restrict__ fnt,
                           const float* __restrict__ sim_src,
                           const float* __restrict__ sim_tgt,
                           const int* __restrict__ labels,
                           float* __restrict__ Sout,   // [y*2+z][BB]
                           float* __restrict__ Cout) {
  const int rb = blockIdx.x * 64;
  const int y  = blockIdx.y;
  const int z  = blockIdx.z;
  const unsigned short* Fb = y ? Ftb : Fsb;
  const float* fn  = y ? fnt : fns;
  const float* sim = y ? sim_tgt : sim_src;

  const int tid = threadIdx.x;
  const int w   = tid >> 6;       // 0..3
  const int l   = tid & 63;
  const int wm  = w >> 1;         // row half
  const int wn  = w & 1;          // col half
  const int l15 = l & 15;
  const int lg  = l >> 4;         // 0..3

  // per-lane row metadata (C/D-layout rows: (lg*4 + r))
  float fnr[2][4];
  int   labr[2][4];
  #pragma unroll
  for (int mr = 0; mr < 2; mr++)
    #pragma unroll
    for (int r = 0; r < 4; r++) {
      int row = rb + wm * 32 + mr * 16 + lg * 4 + r;
      fnr[mr][r]  = fn[row];
      labr[mr][r] = (y == 0) ? labels[row] : -1;
    }

  // A fragments, register-resident for whole block (A-layout rows: l15)
  short8 af[2][4];
  #pragma unroll
  for (int mr = 0; mr < 2; mr++) {
    int row = rb + wm * 32 + mr * 16 + l15;
    const short8* p = (const short8*)&Fb[row * DD];
    #pragma unroll
    for (int ks = 0; ks < 4; ks++) af[mr][ks] = p[ks * 4 + lg];
  }

  float S[2][4]  = {{0.f,0.f,0.f,0.f},{0.f,0.f,0.f,0.f}};
  float Cn[2][4] = {{0.f,0.f,0.f,0.f},{0.f,0.f,0.f,0.f}};

  // 63 tiles of 64 cols cover cols 0..4031 (>= CC beyond 4000 masked off)
  const int t0 = z * 32;
  int t1 = t0 + 32; if (t1 > 63) t1 = 63;

  for (int tt = t0; tt < t1; tt++) {
    const int cb = tt * 64;
    short8 bfr[2][4];
    float  ant[2];
    #pragma unroll
    for (int nr = 0; nr < 2; nr++) {
      int arow = cb + wn * 32 + nr * 16 + l15;
      const short8* p = (const short8*)&Ab[arow * DD];
      #pragma unroll
      for (int ks = 0; ks < 4; ks++) bfr[nr][ks] = p[ks * 4 + lg];
      ant[nr] = an[arow];
    }
    #pragma unroll
    for (int mr = 0; mr < 2; mr++) {
      #pragma unroll
      for (int nr = 0; nr < 2; nr++) {
        f32x4 acc = {0.f, 0.f, 0.f, 0.f};
        #pragma unroll
        for (int ks = 0; ks < 4; ks++)
          acc = __builtin_amdgcn_mfma_f32_16x16x32_bf16(af[mr][ks], bfr[nr][ks], acc, 0, 0, 0);
        const int colg = cb + wn * 32 + nr * 16 + l15;
        const bool inb = colg < CC;
        #pragma unroll
        for (int r = 0; r < 4; r++) {
          const int rowg = rb + wm * 32 + mr * 16 + lg * 4 + r;
          float dist = fnr[mr][r] + ant[nr] - 2.f * acc[r];
          float h = fmaxf(0.f, 1.f - dist);
          float s = inb ? sim[rowg * CC + colg] : 0.f;
          bool msk = inb && (s > 0.5f) && (colg != labr[mr][r]);
          if (msk) { S[mr][r] += h; Cn[mr][r] += 1.f; }
        }
      }
    }
  }

  // reduce over the 16 column-lanes of each group
  #pragma unroll
  for (int mr = 0; mr < 2; mr++)
    #pragma unroll
    for (int r = 0; r < 4; r++) {
      float s = S[mr][r], c = Cn[mr][r];
      #pragma unroll
      for (int m = 1; m < 16; m <<= 1) { s += __shfl_xor(s, m); c += __shfl_xor(c, m); }
      S[mr][r] = s; Cn[mr][r] = c;
    }

  // combine the two wn halves via LDS (deterministic, no atomics)
  __shared__ float lS[64], lC[64];
  if (wn == 1 && l15 == 0) {
    #pragma unroll
    for (int mr = 0; mr < 2; mr++)
      #pragma unroll
      for (int r = 0; r < 4; r++) {
        int rl = wm * 32 + mr * 16 + lg * 4 + r;
        lS[rl] = S[mr][r]; lC[rl] = Cn[mr][r];
      }
  }
  __syncthreads();
  if (wn == 0 && l15 == 0) {
    #pragma unroll
    for (int mr = 0; mr < 2; mr++)
      #pragma unroll
      for (int r = 0; r < 4; r++) {
        int rl = wm * 32 + mr * 16 + lg * 4 + r;
        int idx = (y * 2 + z) * BB + rb + rl;
        Sout[idx] = S[mr][r] + lS[rl];
        Cout[idx] = Cn[mr][r] + lC[rl];
      }
  }
}

// ---- kernel 4: final reduction ----
__global__ void finalize_k(const float* __restrict__ lp,
                           const float* __restrict__ Sout,
                           const float* __restrict__ Cout,
                           float* __restrict__ out) {
  const int t = threadIdx.x;  // 1024 threads, 1 block
  double ts = 0.0;
  long long nv = 0;
  for (int b = t; b < BB; b += 1024) {
    ts += (double)lp[b];
    #pragma unroll
    for (int y = 0; y < 2; y++) {
      float s = Sout[(y * 2 + 0) * BB + b] + Sout[(y * 2 + 1) * BB + b];
      float c = Cout[(y * 2 + 0) * BB + b] + Cout[(y * 2 + 1) * BB + b];
      ts += (double)(s / fmaxf(c, 1.f));
      if (c > 0.f) nv++;
    }
  }
  __shared__ double sd[1024];
  __shared__ long long sc[1024];
  sd[t] = ts; sc[t] = nv;
  __syncthreads();
  for (int s2 = 512; s2 > 0; s2 >>= 1) {
    if (t < s2) { sd[t] += sd[t + s2]; sc[t] += sc[t + s2]; }
    __syncthreads();
  }
  if (t == 0) {
    double nterms = (double)BB + (double)sc[0];
    out[0] = (float)(sd[0] / nterms);
  }
}

extern "C" void kernel_launch(void* const* d_in, const int* in_sizes, int n_in,
                              void* d_out, int out_size, void* d_ws, size_t ws_size,
                              hipStream_t stream) {
  const float* features = (const float*)d_in[0];
  const float* agents   = (const float*)d_in[1];
  const int*   labels   = (const int*)d_in[2];
  const float* sim_src  = (const float*)d_in[3];
  const float* ftgt     = (const float*)d_in[4];
  const float* sim_tgt  = (const float*)d_in[5];
  float* out = (float*)d_out;

  char* w = (char*)d_ws;
  unsigned short* Ab  = (unsigned short*)(w);                 // 1,048,576
  float*          an  = (float*)(w + 1048576);                // 16,384
  unsigned short* Fsb = (unsigned short*)(w + 1064960);       // 4,194,304
  unsigned short* Ftb = (unsigned short*)(w + 5259264);       // 4,194,304
  float*          fns = (float*)(w + 9453568);                // 65,536
  float*          fnt = (float*)(w + 9519104);                // 65,536
  float*          lp  = (float*)(w + 9584640);                // 65,536
  float*          So  = (float*)(w + 9650176);                // 262,144
  float*          Co  = (float*)(w + 9912320);                // 262,144  (end 10,174,464)

  prep_agents_k<<<dim3(CP), dim3(64), 0, stream>>>(agents, Ab, an);
  prep_features_k<<<dim3(BB, 2), dim3(64), 0, stream>>>(
      features, ftgt, agents, labels, Fsb, Ftb, fns, fnt, lp);
  neg_kernel<<<dim3(BB / 64, 2, 2), dim3(256), 0, stream>>>(
      Fsb, Ftb, Ab, an, fns, fnt, sim_src, sim_tgt, labels, So, Co);
  finalize_k<<<dim3(1), dim3(1024), 0, stream>>>(lp, So, Co, out);
}

// Round 2
// 300.076 us; speedup vs baseline: 1.2034x; 1.2034x over previous
//
#include <hip/hip_runtime.h>
#include <hip/hip_bf16.h>

#define BB 16384   // batch
#define CC 4000    // agents (real)
#define CP 4096    // agents padded
#define DD 128     // feature dim

typedef __attribute__((ext_vector_type(8))) short short8;
typedef __attribute__((ext_vector_type(4))) float f32x4;

static __device__ __forceinline__ unsigned short f2bf(float f) {
  union { float f; unsigned int u; } v; v.f = f;
  unsigned int u = v.u;
  u += 0x7fffu + ((u >> 16) & 1u);   // RNE
  return (unsigned short)(u >> 16);
}

// ---- kernel 1: agents -> bf16 (padded to CP rows, zeros) + ||a||^2 ----
__global__ void prep_agents_k(const float* __restrict__ agents,
                              unsigned short* __restrict__ Ab,
                              float* __restrict__ an) {
  int t = threadIdx.x & 63;
  int c = blockIdx.x * 4 + (threadIdx.x >> 6);
  float n = 0.f;
  unsigned int pack = 0u;
  if (c < CC) {
    float2 f = *(const float2*)&agents[c * DD + t * 2];
    n = f.x * f.x + f.y * f.y;
    pack = ((unsigned int)f2bf(f.y) << 16) | (unsigned int)f2bf(f.x);
  }
  ((unsigned int*)Ab)[c * (DD / 2) + t] = pack;
  #pragma unroll
  for (int m = 1; m < 64; m <<= 1) n += __shfl_xor(n, m);
  if (t == 0) an[c] = n;
}

// ---- kernel 2: features -> bf16 + ||f||^2 ; loss_pos exact; sim at label ----
__global__ void prep_features_k(const float* __restrict__ fsrc,
                                const float* __restrict__ ftgt,
                                const float* __restrict__ agents,
                                const int* __restrict__ labels,
                                const float* __restrict__ sim_src,
                                unsigned short* __restrict__ Fsb,
                                unsigned short* __restrict__ Ftb,
                                float* __restrict__ fns,
                                float* __restrict__ fnt,
                                float* __restrict__ lp,
                                float* __restrict__ slab) {
  int t = threadIdx.x & 63;
  int b = blockIdx.x * 4 + (threadIdx.x >> 6);
  int y = blockIdx.y;
  const float* F = y ? ftgt : fsrc;
  unsigned short* Fb = y ? Ftb : Fsb;
  float2 f = *(const float2*)&F[b * DD + t * 2];
  float n = f.x * f.x + f.y * f.y;
  ((unsigned int*)Fb)[b * (DD / 2) + t] =
      ((unsigned int)f2bf(f.y) << 16) | (unsigned int)f2bf(f.x);
  float pl = 0.f;
  int lab = 0;
  if (y == 0) {
    lab = labels[b];
    float2 a = *(const float2*)&agents[lab * DD + t * 2];
    float dx = f.x - a.x, dy = f.y - a.y;
    pl = dx * dx + dy * dy;
  }
  #pragma unroll
  for (int m = 1; m < 64; m <<= 1) { n += __shfl_xor(n, m); pl += __shfl_xor(pl, m); }
  if (t == 0) {
    if (y) fnt[b] = n; else fns[b] = n;
    if (y == 0) {
      lp[b] = pl;
      slab[b] = sim_src[b * CC + lab];
    }
  }
}

// ---- kernel 3: masked hinge over dist = fn + an - 2 f.a  (swapped MFMA) ----
// A=agents tile, B=features tile -> C/D: col(l15)=feature row, row(lg*4+r)=agent col.
// grid (BB/64, 2 {src,tgt}, 4 col-quarters); block 256 = 4 waves in 2x2.
__global__ __launch_bounds__(256, 4)
void neg_kernel(const unsigned short* __restrict__ Fsb,
                const unsigned short* __restrict__ Ftb,
                const unsigned short* __restrict__ Ab,
                const float* __restrict__ an,
                const float* __restrict__ fns,
                const float* __restrict__ fnt,
                const float* __restrict__ sim_src,
                const float* __restrict__ sim_tgt,
                float* __restrict__ Sout,   // [y*4+z][BB]
                float* __restrict__ Cout) {
  const int rb = blockIdx.x * 64;
  const int y  = blockIdx.y;
  const int z  = blockIdx.z;
  const unsigned short* Fb = y ? Ftb : Fsb;
  const float* fn  = y ? fnt : fns;
  const float* sim = y ? sim_tgt : sim_src;

  const int tid = threadIdx.x;
  const int w   = tid >> 6;       // 0..3
  const int l   = tid & 63;
  const int wm  = w >> 1;         // feature-row half
  const int wn  = w & 1;          // agent-col half
  const int l15 = l & 15;
  const int lg  = l >> 4;         // 0..3

  // per-lane feature rows (C/D cols) + register-resident F fragments (B-operand)
  int   frow[2];
  float fnc[2];
  short8 af[2][4];
  #pragma unroll
  for (int mr = 0; mr < 2; mr++) {
    frow[mr] = rb + wm * 32 + mr * 16 + l15;
    fnc[mr]  = 1.f - fn[frow[mr]];
    const short8* p = (const short8*)&Fb[frow[mr] * DD];
    #pragma unroll
    for (int ks = 0; ks < 4; ks++) af[mr][ks] = p[ks * 4 + lg];
  }

  float S[2]  = {0.f, 0.f};
  float Cn[2] = {0.f, 0.f};

  // 63 tiles of 64 cols cover 0..4031 (cols >= CC masked via skipped sim load)
  const int t0 = z * 16;
  const int t1 = (t0 + 16 < 63) ? t0 + 16 : 63;

  for (int tt = t0; tt < t1; tt++) {
    const int cb = tt * 64 + wn * 32;

    // sim loads first (HBM stream; float4 per lane per sub-tile)
    float4 sv[2][2];
    #pragma unroll
    for (int mr = 0; mr < 2; mr++)
      #pragma unroll
      for (int nr = 0; nr < 2; nr++) {
        const int col0 = cb + nr * 16 + lg * 4;
        float4 s4 = make_float4(0.f, 0.f, 0.f, 0.f);
        if (col0 < CC) s4 = *(const float4*)&sim[frow[mr] * CC + col0];
        sv[mr][nr] = s4;
      }

    float4 ant[2];
    short8 bfr[2][4];
    #pragma unroll
    for (int nr = 0; nr < 2; nr++) {
      const int ac = cb + nr * 16;
      ant[nr] = *(const float4*)&an[ac + lg * 4];
      const short8* p = (const short8*)&Ab[(ac + l15) * DD];
      #pragma unroll
      for (int ks = 0; ks < 4; ks++) bfr[nr][ks] = p[ks * 4 + lg];
    }

    #pragma unroll
    for (int mr = 0; mr < 2; mr++) {
      #pragma unroll
      for (int nr = 0; nr < 2; nr++) {
        f32x4 acc = {0.f, 0.f, 0.f, 0.f};
        #pragma unroll
        for (int ks = 0; ks < 4; ks++)
          acc = __builtin_amdgcn_mfma_f32_16x16x32_bf16(bfr[nr][ks], af[mr][ks], acc, 0, 0, 0);
        const float* sp = (const float*)&sv[mr][nr];
        const float* ap = (const float*)&ant[nr];
        #pragma unroll
        for (int r = 0; r < 4; r++) {
          // 1 - dist = (1 - fn - an) + 2*acc
          float c  = fnc[mr] - ap[r];
          float t2 = fmaf(2.f, acc[r], c);
          float h  = fmaxf(0.f, t2);
          bool  m  = sp[r] > 0.5f;
          S[mr]  += m ? h : 0.f;
          Cn[mr] += m ? 1.f : 0.f;
        }
      }
    }
  }

  // reduce across the 4 lane-groups (same l15 = same feature row)
  #pragma unroll
  for (int mr = 0; mr < 2; mr++) {
    float s = S[mr], c = Cn[mr];
    s += __shfl_xor(s, 16); s += __shfl_xor(s, 32);
    c += __shfl_xor(c, 16); c += __shfl_xor(c, 32);
    S[mr] = s; Cn[mr] = c;
  }

  __shared__ float lS[2][64], lC[2][64];
  if (lg == 0) {
    #pragma unroll
    for (int mr = 0; mr < 2; mr++) {
      int rl = wm * 32 + mr * 16 + l15;
      lS[wn][rl] = S[mr]; lC[wn][rl] = Cn[mr];
    }
  }
  __syncthreads();
  if (tid < 64) {
    int idx = (y * 4 + z) * BB + rb + tid;
    Sout[idx] = lS[0][tid] + lS[1][tid];
    Cout[idx] = lC[0][tid] + lC[1][tid];
  }
}

// ---- kernel 4: final reduction (label correction folded in) ----
__global__ void finalize_k(const float* __restrict__ lp,
                           const float* __restrict__ slab,
                           const float* __restrict__ Sout,
                           const float* __restrict__ Cout,
                           float* __restrict__ out) {
  const int t = threadIdx.x;  // 1024 threads, 1 block
  double ts = 0.0;
  long long nv = 0;
  for (int b = t; b < BB; b += 1024) {
    ts += (double)lp[b];
    // src (chunks 0..3), with label-column correction
    float s = 0.f, c = 0.f;
    #pragma unroll
    for (int z = 0; z < 4; z++) { s += Sout[z * BB + b]; c += Cout[z * BB + b]; }
    if (slab[b] > 0.5f) { s -= fmaxf(0.f, 1.f - lp[b]); c -= 1.f; }
    ts += (double)(s / fmaxf(c, 1.f));
    if (c > 0.f) nv++;
    // tgt (chunks 4..7)
    s = 0.f; c = 0.f;
    #pragma unroll
    for (int z = 4; z < 8; z++) { s += Sout[z * BB + b]; c += Cout[z * BB + b]; }
    ts += (double)(s / fmaxf(c, 1.f));
    if (c > 0.f) nv++;
  }
  __shared__ double sd[1024];
  __shared__ long long sc[1024];
  sd[t] = ts; sc[t] = nv;
  __syncthreads();
  for (int s2 = 512; s2 > 0; s2 >>= 1) {
    if (t < s2) { sd[t] += sd[t + s2]; sc[t] += sc[t + s2]; }
    __syncthreads();
  }
  if (t == 0) {
    double nterms = (double)BB + (double)sc[0];
    out[0] = (float)(sd[0] / nterms);
  }
}

extern "C" void kernel_launch(void* const* d_in, const int* in_sizes, int n_in,
                              void* d_out, int out_size, void* d_ws, size_t ws_size,
                              hipStream_t stream) {
  const float* features = (const float*)d_in[0];
  const float* agents   = (const float*)d_in[1];
  const int*   labels   = (const int*)d_in[2];
  const float* sim_src  = (const float*)d_in[3];
  const float* ftgt     = (const float*)d_in[4];
  const float* sim_tgt  = (const float*)d_in[5];
  float* out = (float*)d_out;

  char* w = (char*)d_ws;
  unsigned short* Ab  = (unsigned short*)(w);                 // 1,048,576
  float*          an  = (float*)(w + 1048576);                // 16,384 (CP*4)
  unsigned short* Fsb = (unsigned short*)(w + 1064960);       // 4,194,304
  unsigned short* Ftb = (unsigned short*)(w + 5259264);       // 4,194,304
  float*          fns = (float*)(w + 9453568);                // 65,536
  float*          fnt = (float*)(w + 9519104);                // 65,536
  float*          lp  = (float*)(w + 9584640);                // 65,536
  float*          slab= (float*)(w + 9650176);                // 65,536
  float*          So  = (float*)(w + 9715712);                // 524,288 (8*BB*4)
  float*          Co  = (float*)(w + 10240000);               // 524,288 (end 10,764,288)

  prep_agents_k<<<dim3(CP / 4), dim3(256), 0, stream>>>(agents, Ab, an);
  prep_features_k<<<dim3(BB / 4, 2), dim3(256), 0, stream>>>(
      features, ftgt, agents, labels, sim_src, Fsb, Ftb, fns, fnt, lp, slab);
  neg_kernel<<<dim3(BB / 64, 2, 4), dim3(256), 0, stream>>>(
      Fsb, Ftb, Ab, an, fns, fnt, sim_src, sim_tgt, So, Co);
  finalize_k<<<dim3(1), dim3(1024), 0, stream>>>(lp, slab, So, Co, out);
}

// Round 3
// 169.232 us; speedup vs baseline: 2.1339x; 1.7732x over previous
//
#include <hip/hip_runtime.h>
#include <hip/hip_bf16.h>

#define BB 16384   // batch
#define CC 4000    // agents (real)
#define CP 4096    // agents padded
#define DD 128     // feature dim
#define NT 16      // row-tiles per neg block (64 rows each)

typedef __attribute__((ext_vector_type(8))) short short8;
typedef __attribute__((ext_vector_type(4))) float f32x4;

typedef const __attribute__((address_space(1))) void* gas_ptr;
typedef __attribute__((address_space(3))) void* las_ptr;

static __device__ __forceinline__ unsigned short f2bf(float f) {
  union { float f; unsigned int u; } v; v.f = f;
  unsigned int u = v.u;
  u += 0x7fffu + ((u >> 16) & 1u);   // RNE
  return (unsigned short)(u >> 16);
}

// ---- kernel 1: agents -> bf16 (padded to CP rows, zeros) + ||a||^2 ; zbuf ----
__global__ void prep_agents_k(const float* __restrict__ agents,
                              unsigned short* __restrict__ Ab,
                              float* __restrict__ an,
                              float* __restrict__ zbuf) {
  int t = threadIdx.x & 63;
  int c = blockIdx.x * 4 + (threadIdx.x >> 6);
  if (blockIdx.x == 0 && threadIdx.x < 64) zbuf[threadIdx.x] = 0.f;
  float n = 0.f;
  unsigned int pack = 0u;
  if (c < CC) {
    float2 f = *(const float2*)&agents[c * DD + t * 2];
    n = f.x * f.x + f.y * f.y;
    pack = ((unsigned int)f2bf(f.y) << 16) | (unsigned int)f2bf(f.x);
  }
  ((unsigned int*)Ab)[c * (DD / 2) + t] = pack;
  #pragma unroll
  for (int m = 1; m < 64; m <<= 1) n += __shfl_xor(n, m);
  if (t == 0) an[c] = n;
}

// ---- kernel 2: features -> bf16 + ||f||^2 ; loss_pos exact; sim at label;
//      zero the atomic accumulators ----
__global__ void prep_features_k(const float* __restrict__ fsrc,
                                const float* __restrict__ ftgt,
                                const float* __restrict__ agents,
                                const int* __restrict__ labels,
                                const float* __restrict__ sim_src,
                                unsigned short* __restrict__ Fsb,
                                unsigned short* __restrict__ Ftb,
                                float* __restrict__ fns,
                                float* __restrict__ fnt,
                                float* __restrict__ lp,
                                float* __restrict__ slab,
                                float* __restrict__ Sat,
                                float* __restrict__ Cat) {
  int t = threadIdx.x & 63;
  int b = blockIdx.x * 4 + (threadIdx.x >> 6);
  int y = blockIdx.y;
  const float* F = y ? ftgt : fsrc;
  unsigned short* Fb = y ? Ftb : Fsb;
  float2 f = *(const float2*)&F[b * DD + t * 2];
  float n = f.x * f.x + f.y * f.y;
  ((unsigned int*)Fb)[b * (DD / 2) + t] =
      ((unsigned int)f2bf(f.y) << 16) | (unsigned int)f2bf(f.x);
  float pl = 0.f;
  int lab = 0;
  if (y == 0) {
    lab = labels[b];
    float2 a = *(const float2*)&agents[lab * DD + t * 2];
    float dx = f.x - a.x, dy = f.y - a.y;
    pl = dx * dx + dy * dy;
  }
  #pragma unroll
  for (int m = 1; m < 64; m <<= 1) { n += __shfl_xor(n, m); pl += __shfl_xor(pl, m); }
  if (t == 0) {
    if (y) fnt[b] = n; else fns[b] = n;
    if (y == 0) {
      lp[b] = pl;
      slab[b] = sim_src[b * CC + lab];
    }
    Sat[y * BB + b] = 0.f;
    Cat[y * BB + b] = 0.f;
  }
}

// ---- kernel 3: masked hinge; agents register-resident, sim via global_load_lds ----
// grid (CP/64 col-blocks, BB/1024 row-splits, 2 {src,tgt}); block 256 = 4 waves.
// Wave w owns rows [rbase + t*64 + w*16, +16) each iter; cols = block's 64.
__global__ __launch_bounds__(256, 2)
void neg_kernel(const unsigned short* __restrict__ Fsb,
                const unsigned short* __restrict__ Ftb,
                const unsigned short* __restrict__ Ab,
                const float* __restrict__ an,
                const float* __restrict__ fns,
                const float* __restrict__ fnt,
                const float* __restrict__ sim_src,
                const float* __restrict__ sim_tgt,
                const float* __restrict__ zbuf,
                float* __restrict__ Sat,
                float* __restrict__ Cat) {
  const int cb    = blockIdx.x * 64;          // agent col base
  const int rbase = blockIdx.y * (64 * NT);   // feature row base
  const int y     = blockIdx.z;
  const unsigned short* Fb = y ? Ftb : Fsb;
  const float* fn  = y ? fnt : fns;
  const float* sim = y ? sim_tgt : sim_src;
  float* Sp = Sat + y * BB;
  float* Cp = Cat + y * BB;

  const int tid = threadIdx.x;
  const int w   = tid >> 6;
  const int l   = tid & 63;
  const int l15 = l & 15;
  const int lg  = l >> 4;

  __shared__ float simlds[2][4][1024];   // [buf][wave][16 rows x 64 cols]

  // agents: A-frags + an, register-resident for the whole kernel
  short8 af[4][4];
  float4 av[4];
  #pragma unroll
  for (int nr = 0; nr < 4; nr++) {
    const short8* p = (const short8*)&Ab[(cb + nr * 16 + l15) * DD];
    #pragma unroll
    for (int ks = 0; ks < 4; ks++) af[nr][ks] = p[ks * 4 + lg];
    av[nr] = *(const float4*)&an[cb + nr * 16 + lg * 4];
  }

  // sim staging source pointers (per lane, 4 gll instrs j=0..3)
  // LDS linear dest byte = j*1024 + lane*16 -> (row = j*4+lg, slot = l15);
  // content must be sim[row][cb + (slot ^ (row&7))*4 .. +3]  (XOR pre-swizzle)
  const char* sp_[4];
  long step_[4];
  #pragma unroll
  for (int j = 0; j < 4; j++) {
    int row  = j * 4 + lg;
    int c16  = l15 ^ (row & 7);
    bool valid = (cb + c16 * 4) < CC;
    sp_[j] = valid
        ? (const char*)&sim[(size_t)(rbase + w * 16 + row) * CC + cb + c16 * 4]
        : (const char*)zbuf;
    step_[j] = valid ? (long)(64 * (size_t)CC * 4) : 0;
  }

  const unsigned short* fptr = &Fb[(size_t)(rbase + w * 16 + l15) * DD];
  const float* fnptr = &fn[rbase + w * 16 + l15];

  auto stage = [&](int buf) {
    #pragma unroll
    for (int j = 0; j < 4; j++) {
      __builtin_amdgcn_global_load_lds((gas_ptr)(const void*)sp_[j],
                                       (las_ptr)(void*)&simlds[buf][w][j * 256],
                                       16, 0, 0);
      sp_[j] += step_[j];
    }
  };

  auto loadF = [&](short8 (&ff)[4], float& fnc1) {
    const short8* p = (const short8*)fptr;
    #pragma unroll
    for (int ks = 0; ks < 4; ks++) ff[ks] = p[ks * 4 + lg];
    fnc1 = 1.f - *fnptr;
    fptr  += 64 * DD;
    fnptr += 64;
  };

  auto body = [&](int buf, const short8 (&ff)[4], float fnc1, int t) {
    float4 sv[4];
    #pragma unroll
    for (int nr = 0; nr < 4; nr++) {
      int slot = (nr * 4 + lg) ^ (l15 & 7);
      sv[nr] = *(const float4*)&simlds[buf][w][l15 * 64 + slot * 4];
    }
    float rowS = 0.f, rowC = 0.f;
    #pragma unroll
    for (int nr = 0; nr < 4; nr++) {
      f32x4 acc = {0.f, 0.f, 0.f, 0.f};
      #pragma unroll
      for (int ks = 0; ks < 4; ks++)
        acc = __builtin_amdgcn_mfma_f32_16x16x32_bf16(af[nr][ks], ff[ks], acc, 0, 0, 0);
      const float* ap = (const float*)&av[nr];
      const float* sp = (const float*)&sv[nr];
      #pragma unroll
      for (int r = 0; r < 4; r++) {
        float c0 = fnc1 - ap[r];               // (1 - fn) - an
        float t2 = fmaf(2.f, acc[r], c0);      // 1 - dist
        float h  = fmaxf(0.f, t2);
        bool  m  = sp[r] > 0.5f;
        rowS += m ? h : 0.f;
        rowC += m ? 1.f : 0.f;
      }
    }
    rowS += __shfl_xor(rowS, 16); rowS += __shfl_xor(rowS, 32);
    rowC += __shfl_xor(rowC, 16); rowC += __shfl_xor(rowC, 32);
    if (lg == 0) {
      int row = rbase + t * 64 + w * 16 + l15;
      atomicAdd(&Sp[row], rowS);
      atomicAdd(&Cp[row], rowC);
    }
  };

  short8 ffA[4], ffB[4];
  float fnA, fnB;

  // prologue: tile 0 in flight (9 ops)
  stage(0); loadF(ffA, fnA);

  #pragma unroll 1
  for (int k = 0; k < 7; k++) {
    stage(1); loadF(ffB, fnB);                       // prefetch t=2k+1
    asm volatile("s_waitcnt vmcnt(9)" ::: "memory"); // tile 2k ready
    body(0, ffA, fnA, 2 * k);
    stage(0); loadF(ffA, fnA);                       // prefetch t=2k+2
    asm volatile("s_waitcnt vmcnt(9)" ::: "memory"); // tile 2k+1 ready
    body(1, ffB, fnB, 2 * k + 1);
  }
  stage(1); loadF(ffB, fnB);                         // prefetch t=15
  asm volatile("s_waitcnt vmcnt(9)" ::: "memory");
  body(0, ffA, fnA, 14);
  asm volatile("s_waitcnt vmcnt(0)" ::: "memory");
  body(1, ffB, fnB, 15);
}

// ---- kernel 4: final reduction (label correction folded in) ----
__global__ void finalize_k(const float* __restrict__ lp,
                           const float* __restrict__ slab,
                           const float* __restrict__ Sat,
                           const float* __restrict__ Cat,
                           float* __restrict__ out) {
  const int t = threadIdx.x;  // 1024 threads, 1 block
  double ts = 0.0;
  long long nv = 0;
  for (int b = t; b < BB; b += 1024) {
    ts += (double)lp[b];
    float s = Sat[b], c = Cat[b];
    if (slab[b] > 0.5f) { s -= fmaxf(0.f, 1.f - lp[b]); c -= 1.f; }
    ts += (double)(s / fmaxf(c, 1.f));
    if (c > 0.f) nv++;
    s = Sat[BB + b]; c = Cat[BB + b];
    ts += (double)(s / fmaxf(c, 1.f));
    if (c > 0.f) nv++;
  }
  __shared__ double sd[1024];
  __shared__ long long sc[1024];
  sd[t] = ts; sc[t] = nv;
  __syncthreads();
  for (int s2 = 512; s2 > 0; s2 >>= 1) {
    if (t < s2) { sd[t] += sd[t + s2]; sc[t] += sc[t + s2]; }
    __syncthreads();
  }
  if (t == 0) {
    double nterms = (double)BB + (double)sc[0];
    out[0] = (float)(sd[0] / nterms);
  }
}

extern "C" void kernel_launch(void* const* d_in, const int* in_sizes, int n_in,
                              void* d_out, int out_size, void* d_ws, size_t ws_size,
                              hipStream_t stream) {
  const float* features = (const float*)d_in[0];
  const float* agents   = (const float*)d_in[1];
  const int*   labels   = (const int*)d_in[2];
  const float* sim_src  = (const float*)d_in[3];
  const float* ftgt     = (const float*)d_in[4];
  const float* sim_tgt  = (const float*)d_in[5];
  float* out = (float*)d_out;

  char* wsp = (char*)d_ws;
  unsigned short* Ab  = (unsigned short*)(wsp);                 // 1,048,576
  float*          an  = (float*)(wsp + 1048576);                // 16,384
  unsigned short* Fsb = (unsigned short*)(wsp + 1064960);       // 4,194,304
  unsigned short* Ftb = (unsigned short*)(wsp + 5259264);       // 4,194,304
  float*          fns = (float*)(wsp + 9453568);                // 65,536
  float*          fnt = (float*)(wsp + 9519104);                // 65,536
  float*          lp  = (float*)(wsp + 9584640);                // 65,536
  float*          slab= (float*)(wsp + 9650176);                // 65,536
  float*          Sat = (float*)(wsp + 9715712);                // 131,072 (2*BB*4)
  float*          Cat = (float*)(wsp + 9846784);                // 131,072
  float*          zbuf= (float*)(wsp + 9977856);                // 256     (end 9,978,112)

  prep_agents_k<<<dim3(CP / 4), dim3(256), 0, stream>>>(agents, Ab, an, zbuf);
  prep_features_k<<<dim3(BB / 4, 2), dim3(256), 0, stream>>>(
      features, ftgt, agents, labels, sim_src, Fsb, Ftb, fns, fnt, lp, slab, Sat, Cat);
  neg_kernel<<<dim3(CP / 64, BB / (64 * NT), 2), dim3(256), 0, stream>>>(
      Fsb, Ftb, Ab, an, fns, fnt, sim_src, sim_tgt, zbuf, Sat, Cat);
  finalize_k<<<dim3(1), dim3(1024), 0, stream>>>(lp, slab, Sat, Cat, out);
}